// Round 7
// baseline (217.191 us; speedup 1.0000x reference)
//
#include <hip/hip_runtime.h>
#include <hip/hip_bf16.h>
#include <cstdint>
#include <cstddef>

#define S_LEN 2048
#define N_HEADS 16
#define HD 64
#define EMB 1024
#define N_BATCH 2
#define N_BH (N_BATCH * N_HEADS)

typedef __attribute__((ext_vector_type(4))) float f32x4;
typedef __attribute__((ext_vector_type(16))) float f32x16;
typedef __attribute__((ext_vector_type(8))) short short8;      // 16B raw container
typedef __attribute__((ext_vector_type(8))) _Float16 half8;    // f16 MFMA frag

__device__ __forceinline__ f32x4 mfma16h(half8 a, half8 b, f32x4 c) {
    return __builtin_amdgcn_mfma_f32_16x16x32_f16(a, b, c, 0, 0, 0);
}
__device__ __forceinline__ f32x16 mfma32h(half8 a, half8 b, f32x16 c) {
    return __builtin_amdgcn_mfma_f32_32x32x16_f16(a, b, c, 0, 0, 0);
}

__device__ __forceinline__ unsigned pkh(float a, float b) {
    return __builtin_bit_cast(unsigned, __builtin_amdgcn_cvt_pkrtz(a, b));
}

#if __has_builtin(__builtin_amdgcn_exp2f)
__device__ __forceinline__ float fast_exp2(float x) { return __builtin_amdgcn_exp2f(x); }
#else
__device__ __forceinline__ float fast_exp2(float x) { return exp2f(x); }
#endif

// ---------------------------------------------------------------------------
// Kernel 1 (prep): blocks [0,3072) QKV projection; [3072,5120) mask pack
// (TRANSPOSED: bits[(b*32 + word)][q], coalesced attn reads); [5120,5632)
// Wo fp32->f16.  (unchanged from R6, PASSED)
// ---------------------------------------------------------------------------
__global__ __launch_bounds__(256) void prep_kernel(
    const float* __restrict__ q_in, const float* __restrict__ k_in,
    const float* __restrict__ v_in,
    const float* __restrict__ Wq, const float* __restrict__ Wk,
    const float* __restrict__ Wv, const float* __restrict__ Wo,
    const int* __restrict__ mask,
    short* __restrict__ Qb, short* __restrict__ Kb, short* __restrict__ Vt,
    short* __restrict__ Woh, unsigned long long* __restrict__ bits) {
    __shared__ short Al[64 * 72];
    __shared__ short Wl[64 * 72];
    __shared__ short Ol[64 * 72];
    int bx = blockIdx.x;
    int t = threadIdx.x;

    if (bx >= 3072) {
        if (bx < 5120) {
            int gw = (bx - 3072) * 4 + (t >> 6);
            int lane = t & 63;
            const int* src = mask + (size_t)gw * 1024 + lane;
            int row = gw >> 1;
            int bb = row >> 11, qq = row & 2047;
            int wbase = (gw & 1) * 16;
#pragma unroll
            for (int r = 0; r < 16; r++) {
                unsigned long long w = __ballot(src[r * 64] != 0);
                if (lane == 0)
                    bits[((size_t)(bb * 32 + wbase + r) << 11) + qq] = w;
            }
        } else {
            int i = (bx - 5120) * 256 + t;
            f32x4 a = reinterpret_cast<const f32x4*>(Wo)[i * 2];
            f32x4 b = reinterpret_cast<const f32x4*>(Wo)[i * 2 + 1];
            uint4 u = { pkh(a.x, a.y), pkh(a.z, a.w), pkh(b.x, b.y), pkh(b.z, b.w) };
            reinterpret_cast<uint4*>(Woh)[i] = u;
        }
        return;
    }

    int rt = bx & 31;
    int bh = (bx >> 5) & 31;
    int tz = bx >> 10;
    const float* src = (tz == 0 ? q_in : tz == 1 ? k_in : v_in)
                       + (size_t)bh * S_LEN * HD + (size_t)rt * 64 * HD;
    const float* W = (tz == 0 ? Wq : tz == 1 ? Wk : Wv);

#pragma unroll
    for (int r = 0; r < 4; r++) {
        int f4 = t + 256 * r;
        int row = f4 >> 4;
        int c4 = (f4 & 15) * 4;
        f32x4 a = reinterpret_cast<const f32x4*>(src)[f4];
        uint2 ua = { pkh(a.x, a.y), pkh(a.z, a.w) };
        *reinterpret_cast<uint2*>(&Al[row * 72 + c4]) = ua;
        f32x4 w = reinterpret_cast<const f32x4*>(W)[f4];
        uint2 uw = { pkh(w.x, w.y), pkh(w.z, w.w) };
        *reinterpret_cast<uint2*>(&Wl[row * 72 + c4]) = uw;
    }
    __syncthreads();

    int wave = t >> 6, lane = t & 63, quad = lane >> 4, col = lane & 15;
    half8 a0 = *reinterpret_cast<const half8*>(&Al[(wave * 16 + col) * 72 + quad * 8]);
    half8 a1 = *reinterpret_cast<const half8*>(&Al[(wave * 16 + col) * 72 + 32 + quad * 8]);

    const float C1 = 0.04508422002777448f;  // log2(e)/32
    float scl = (tz == 0) ? C1 : 1.0f;

    f32x4 acc[4];
#pragma unroll
    for (int jt = 0; jt < 4; jt++) {
        half8 b0 = *reinterpret_cast<const half8*>(&Wl[(jt * 16 + col) * 72 + quad * 8]);
        half8 b1 = *reinterpret_cast<const half8*>(&Wl[(jt * 16 + col) * 72 + 32 + quad * 8]);
        f32x4 c = {0.f, 0.f, 0.f, 0.f};
        c = mfma16h(a0, b0, c);
        c = mfma16h(a1, b1, c);
        acc[jt] = c;
    }
    __syncthreads();

    if (tz < 2) {
#pragma unroll
        for (int jt = 0; jt < 4; jt++)
#pragma unroll
            for (int i = 0; i < 4; i++)
                Ol[(wave * 16 + quad * 4 + i) * 72 + jt * 16 + col] =
                    __builtin_bit_cast(short, (_Float16)(acc[jt][i] * scl));
        __syncthreads();
        short* dst = (tz == 0 ? Qb : Kb) + (size_t)bh * S_LEN * HD + (size_t)rt * 64 * HD;
        int row = t >> 2, ck = (t & 3) * 16;
        short8 o0 = *reinterpret_cast<const short8*>(&Ol[row * 72 + ck]);
        short8 o1 = *reinterpret_cast<const short8*>(&Ol[row * 72 + ck + 8]);
        *reinterpret_cast<short8*>(&dst[row * 64 + ck]) = o0;
        *reinterpret_cast<short8*>(&dst[row * 64 + ck + 8]) = o1;
    } else {
#pragma unroll
        for (int jt = 0; jt < 4; jt++)
#pragma unroll
            for (int i = 0; i < 4; i++)
                Ol[(jt * 16 + col) * 72 + wave * 16 + quad * 4 + i] =
                    __builtin_bit_cast(short, (_Float16)acc[jt][i]);
        __syncthreads();
        short* dst = Vt + (size_t)bh * HD * S_LEN + rt * 64;
        int d = t >> 2, ck = (t & 3) * 16;
        short8 o0 = *reinterpret_cast<const short8*>(&Ol[d * 72 + ck]);
        short8 o1 = *reinterpret_cast<const short8*>(&Ol[d * 72 + ck + 8]);
        *reinterpret_cast<short8*>(&dst[(size_t)d * S_LEN + ck]) = o0;
        *reinterpret_cast<short8*>(&dst[(size_t)d * S_LEN + ck + 8]) = o1;
    }
}

// ---------------------------------------------------------------------------
// Kernel 2: flash attention. 256 thr = 4 waves = 2 q-groups(32q) x 2 kv-halves
// (additive split).  Grid (32,32) = 1024 blocks = 4 blocks/CU (16 waves).
// NEW: P never touches LDS — the S^T C-layout and PV B-layout differ only in
// which 16-lane half holds kv mod 8; lane pairs (l, l^32) exchange 8 packed
// dwords via shfl_xor(32) + selects to build both PV B-frags in-register.
// LDS = K/V double buffer (32KB) only; 1 barrier/tile; zero P bank conflicts.
// ---------------------------------------------------------------------------
__global__ __launch_bounds__(256, 4) void attn_kernel(
    const short* __restrict__ Qb, const short* __restrict__ Kb,
    const short* __restrict__ Vt, const unsigned long long* __restrict__ mbits,
    short* __restrict__ Xb) {
    int qt = blockIdx.x;  // 0..31
    int bh = blockIdx.y;  // 0..31
    int b = bh >> 4;
    int t = threadIdx.x, wave = t >> 6, lane = t & 63;
    int g = wave & 1, h = wave >> 1;
    int l5 = lane >> 5, l31 = lane & 31;

    // LDS: [0,16384) shorts: K/V double buffer (buf b: K at b*8192, V at +4096)
    // [16384,16512): lbuf (64 floats). obuf (16KB floats) overlays KV after loop.
    __shared__ short smem[16512];
    float* lbuf = (float*)(smem + 16384);

    const short* Qh = Qb + (size_t)bh * S_LEN * HD;
    const short* Kh = Kb + (size_t)bh * S_LEN * HD;
    const short* Vh = Vt + (size_t)bh * HD * S_LEN;
    int qbase = qt * 64 + g * 32;
    int q = qbase + l31;

    half8 qf[4];
#pragma unroll
    for (int kc = 0; kc < 4; kc++)
        qf[kc] = *reinterpret_cast<const half8*>(&Qh[(size_t)q * HD + kc * 16 + l5 * 8]);

    const unsigned long long* mcol = mbits + ((size_t)(b * 32) << 11);
    unsigned long long mwq = mcol[q];

    // staging: K tile 512 chunks + V tile 512 chunks; 2 K + 2 V per thread
    int r0 = t >> 3, r1 = r0 + 32, cc = t & 7;
    int dst0 = r0 * 64 + ((cc ^ (r0 & 7)) * 8);
    int dst1 = r1 * 64 + ((cc ^ (r1 & 7)) * 8);
    const short* kg0 = Kh + r0 * HD + cc * 8;             // +4096 per tile
    const short* kg1 = Kh + r1 * HD + cc * 8;
    const short* vg0 = Vh + (size_t)r0 * S_LEN + cc * 8;  // +64 per tile
    const short* vg1 = Vh + (size_t)r1 * S_LEN + cc * 8;

    short8 pk0 = *reinterpret_cast<const short8*>(kg0);
    short8 pk1 = *reinterpret_cast<const short8*>(kg1);
    short8 pv0 = *reinterpret_cast<const short8*>(vg0);
    short8 pv1 = *reinterpret_cast<const short8*>(vg1);
    *reinterpret_cast<short8*>(&smem[dst0]) = pk0;
    *reinterpret_cast<short8*>(&smem[dst1]) = pk1;
    *reinterpret_cast<short8*>(&smem[4096 + dst0]) = pv0;
    *reinterpret_cast<short8*>(&smem[4096 + dst1]) = pv1;
    __syncthreads();

    f32x16 o0, o1;
#pragma unroll
    for (int r = 0; r < 16; r++) { o0[r] = 0.f; o1[r] = 0.f; }
    float l_acc = 0.f;
    int krow = h * 32 + l31;

    for (int kt = 0; kt < 32; kt++) {
        unsigned long long mwq_n;
        if (kt < 31) {
            pk0 = *reinterpret_cast<const short8*>(kg0 + (kt + 1) * 4096);
            pk1 = *reinterpret_cast<const short8*>(kg1 + (kt + 1) * 4096);
            pv0 = *reinterpret_cast<const short8*>(vg0 + (kt + 1) * 64);
            pv1 = *reinterpret_cast<const short8*>(vg1 + (kt + 1) * 64);
            mwq_n = mcol[((size_t)(kt + 1) << 11) + q];
        }
        const short* Kbs = smem + (kt & 1) * 8192;
        const short* Vbs = Kbs + 4096;

        // ---- S^T = K·Q^T for this wave's kv-half (4 MFMAs) ----
        f32x16 s;
#pragma unroll
        for (int r = 0; r < 16; r++) s[r] = 0.f;
#pragma unroll
        for (int kc = 0; kc < 4; kc++) {
            half8 ka = *reinterpret_cast<const half8*>(
                &Kbs[krow * 64 + (((kc * 2 + l5) ^ (krow & 7)) * 8)]);
            s = mfma32h(ka, qf[kc], s);
        }
        // ---- lane-local softmax numerator ----
        unsigned gs = (unsigned)(mwq >> (h * 32)) >> (4 * l5);
        float pr[16];
#pragma unroll
        for (int r = 0; r < 16; r++) {
            int bitc = (r & 3) + 8 * (r >> 2);
            pr[r] = fast_exp2(((gs >> bitc) & 1u) ? s[r] : -200.0f);
            l_acc += pr[r];
        }
        // ---- in-register transpose to PV B-frags (no LDS) ----
        unsigned uu[8], xx[8];
#pragma unroll
        for (int i = 0; i < 8; i++) uu[i] = pkh(pr[2 * i], pr[2 * i + 1]);
#pragma unroll
        for (int i = 0; i < 8; i++)
            xx[i] = (unsigned)__shfl_xor((int)uu[i], 32);
        uint4 b0u, b1u;
        b0u.x = l5 ? xx[2] : uu[0]; b0u.y = l5 ? xx[3] : uu[1];
        b0u.z = l5 ? uu[2] : xx[0]; b0u.w = l5 ? uu[3] : xx[1];
        b1u.x = l5 ? xx[6] : uu[4]; b1u.y = l5 ? xx[7] : uu[5];
        b1u.z = l5 ? uu[6] : xx[4]; b1u.w = l5 ? uu[7] : xx[5];
        half8 pb0 = __builtin_bit_cast(half8, b0u);
        half8 pb1 = __builtin_bit_cast(half8, b1u);

        // ---- O^T += V^T · P^T over this kv-half (4 MFMAs) ----
        {
            half8 va = *reinterpret_cast<const half8*>(
                &Vbs[l31 * 64 + (((h * 4 + l5) ^ (l31 & 7)) * 8)]);
            o0 = mfma32h(va, pb0, o0);
        }
        {
            int vr = 32 + l31;
            half8 va = *reinterpret_cast<const half8*>(
                &Vbs[vr * 64 + (((h * 4 + l5) ^ (vr & 7)) * 8)]);
            o1 = mfma32h(va, pb0, o1);
        }
        {
            half8 va = *reinterpret_cast<const half8*>(
                &Vbs[l31 * 64 + (((h * 4 + 2 + l5) ^ (l31 & 7)) * 8)]);
            o0 = mfma32h(va, pb1, o0);
        }
        {
            int vr = 32 + l31;
            half8 va = *reinterpret_cast<const half8*>(
                &Vbs[vr * 64 + (((h * 4 + 2 + l5) ^ (vr & 7)) * 8)]);
            o1 = mfma32h(va, pb1, o1);
        }
        // ---- stage next tile into other buffer, single barrier ----
        if (kt < 31) {
            short* nb = smem + ((kt + 1) & 1) * 8192;
            *reinterpret_cast<short8*>(&nb[dst0]) = pk0;
            *reinterpret_cast<short8*>(&nb[dst1]) = pk1;
            *reinterpret_cast<short8*>(&nb[4096 + dst0]) = pv0;
            *reinterpret_cast<short8*>(&nb[4096 + dst1]) = pv1;
            mwq = mwq_n;
        }
        __syncthreads();
    }

    // ---- combine kv-halves (additive split) ----
    l_acc += __shfl_xor(l_acc, 32);
    float* obuf = (float*)smem;  // 64 rows x 64 lanes fp32 = 16KB, overlays KV
    if (h == 1) {
#pragma unroll
        for (int r = 0; r < 16; r++) {
            obuf[(g * 32 + r) * 64 + lane] = o0[r];
            obuf[(g * 32 + 16 + r) * 64 + lane] = o1[r];
        }
        if (lane < 32) lbuf[g * 32 + lane] = l_acc;
    }
    __syncthreads();
    if (h == 0) {
        float inv = 1.0f / (l_acc + lbuf[g * 32 + l31]);
#pragma unroll
        for (int r = 0; r < 16; r++) {
            o0[r] = (o0[r] + obuf[(g * 32 + r) * 64 + lane]) * inv;
            o1[r] = (o1[r] + obuf[(g * 32 + 16 + r) * 64 + lane]) * inv;
        }
        short* Xrow = Xb + (size_t)bh * S_LEN * HD + (size_t)q * HD;
#pragma unroll
        for (int u = 0; u < 4; u++) {
            uint2 w0 = { pkh(o0[4 * u], o0[4 * u + 1]), pkh(o0[4 * u + 2], o0[4 * u + 3]) };
            *reinterpret_cast<uint2*>(&Xrow[4 * l5 + 8 * u]) = w0;
            uint2 w1 = { pkh(o1[4 * u], o1[4 * u + 1]), pkh(o1[4 * u + 2], o1[4 * u + 3]) };
            *reinterpret_cast<uint2*>(&Xrow[32 + 4 * l5 + 8 * u]) = w1;
        }
    }
}

// ---------------------------------------------------------------------------
// Kernel 3: out = X @ Wo^T + bo.  128m x 64n tile, 512 thr (8 waves x 16 m),
// BK=64, double-buffered staging, 1 barrier/step.  (unchanged from R6)
// ---------------------------------------------------------------------------
__global__ __launch_bounds__(512, 4) void final_kernel(
    const short* __restrict__ Xb, const short* __restrict__ Woh,
    const float* __restrict__ bo, float* __restrict__ out) {
    int nb = blockIdx.x;  // 0..15
    int mb = blockIdx.y;  // 0..31
    int t = threadIdx.x, wave = t >> 6, lane = t & 63, quad = lane >> 4, col = lane & 15;
    __shared__ short smem[24576];

    int m0 = mb * 128, n0 = nb * 64;
    int r0 = t >> 3, r1 = r0 + 64, cc = t & 7;
    int dx0 = r0 * 64 + ((cc ^ (r0 & 7)) * 8);
    int dx1 = r1 * 64 + ((cc ^ (r1 & 7)) * 8);
    const short* xg0 = Xb + (size_t)(m0 + r0) * EMB + cc * 8;   // +64 per step
    const short* xg1 = Xb + (size_t)(m0 + r1) * EMB + cc * 8;
    const short* wg0 = Woh + (size_t)(n0 + r0) * EMB + cc * 8;

    short8 px0 = *reinterpret_cast<const short8*>(xg0);
    short8 px1 = *reinterpret_cast<const short8*>(xg1);
    short8 pw0 = *reinterpret_cast<const short8*>(wg0);
    *reinterpret_cast<short8*>(&smem[dx0]) = px0;
    *reinterpret_cast<short8*>(&smem[dx1]) = px1;
    *reinterpret_cast<short8*>(&smem[16384 + dx0]) = pw0;
    __syncthreads();

    f32x4 acc[4];
#pragma unroll
    for (int nf = 0; nf < 4; nf++) acc[nf] = (f32x4){0.f, 0.f, 0.f, 0.f};
    int arow = wave * 16 + col;

    for (int s = 0; s < 16; s++) {
        if (s < 15) {
            px0 = *reinterpret_cast<const short8*>(xg0 + (s + 1) * 64);
            px1 = *reinterpret_cast<const short8*>(xg1 + (s + 1) * 64);
            pw0 = *reinterpret_cast<const short8*>(wg0 + (s + 1) * 64);
        }
        const short* Xs = smem + (s & 1) * 8192;
        const short* Ws = smem + 16384 + (s & 1) * 4096;
#pragma unroll
        for (int k2 = 0; k2 < 2; k2++) {
            half8 a = *reinterpret_cast<const half8*>(
                &Xs[arow * 64 + (((k2 * 4 + quad) ^ (arow & 7)) * 8)]);
#pragma unroll
            for (int nf = 0; nf < 4; nf++) {
                int brow = nf * 16 + col;
                half8 bf = *reinterpret_cast<const half8*>(
                    &Ws[brow * 64 + (((k2 * 4 + quad) ^ (brow & 7)) * 8)]);
                acc[nf] = mfma16h(a, bf, acc[nf]);
            }
        }
        if (s < 15) {
            short* Xn = smem + ((s + 1) & 1) * 8192;
            short* Wn = smem + 16384 + ((s + 1) & 1) * 4096;
            *reinterpret_cast<short8*>(&Xn[dx0]) = px0;
            *reinterpret_cast<short8*>(&Xn[dx1]) = px1;
            *reinterpret_cast<short8*>(&Wn[dx0]) = pw0;
        }
        __syncthreads();
    }

#pragma unroll
    for (int nf = 0; nf < 4; nf++) {
        int n = n0 + nf * 16 + col;
        float bb = bo[n];
        int rowb = m0 + wave * 16 + quad * 4;
#pragma unroll
        for (int i = 0; i < 4; i++)
            out[(size_t)(rowb + i) * EMB + n] = acc[nf][i] + bb;
    }
}

// ---------------------------------------------------------------------------
extern "C" void kernel_launch(void* const* d_in, const int* in_sizes, int n_in,
                              void* d_out, int out_size, void* d_ws, size_t ws_size,
                              hipStream_t stream) {
    const float* value = (const float*)d_in[0];
    const float* key_  = (const float*)d_in[1];
    const float* query = (const float*)d_in[2];
    const int*   mask  = (const int*)d_in[3];
    const float* Wq = (const float*)d_in[4];
    const float* Wk = (const float*)d_in[5];
    const float* Wv = (const float*)d_in[6];
    const float* Wo = (const float*)d_in[7];
    const float* bo = (const float*)d_in[8];
    float* out = (float*)d_out;

    char* ws = (char*)d_ws;
    short* Qb  = (short*)(ws);
    short* Kb  = (short*)(ws + (size_t)8  * 1048576);
    short* Vt  = (short*)(ws + (size_t)16 * 1048576);
    short* Xb  = (short*)(ws + (size_t)24 * 1048576);
    short* Woh = (short*)(ws + (size_t)32 * 1048576);
    unsigned long long* mbits =
        (unsigned long long*)(ws + (size_t)34 * 1048576);

    prep_kernel<<<dim3(3072 + 2048 + 512), dim3(256), 0, stream>>>(
        query, key_, value, Wq, Wk, Wv, Wo, mask, Qb, Kb, Vt, Woh, mbits);
    attn_kernel<<<dim3(S_LEN / 64, N_BH), dim3(256), 0, stream>>>(Qb, Kb, Vt, mbits, Xb);
    final_kernel<<<dim3(EMB / 64, (N_BATCH * S_LEN) / 128), dim3(512), 0, stream>>>(
        Xb, Woh, bo, out);
}

// Round 8
// 207.542 us; speedup vs baseline: 1.0465x; 1.0465x over previous
//
#include <hip/hip_runtime.h>
#include <hip/hip_bf16.h>
#include <cstdint>
#include <cstddef>

#define S_LEN 2048
#define N_HEADS 16
#define HD 64
#define EMB 1024
#define N_BATCH 2
#define N_BH (N_BATCH * N_HEADS)

typedef __attribute__((ext_vector_type(4))) float f32x4;
typedef __attribute__((ext_vector_type(16))) float f32x16;
typedef __attribute__((ext_vector_type(8))) short short8;      // 16B raw container
typedef __attribute__((ext_vector_type(8))) _Float16 half8;    // f16 MFMA frag

__device__ __forceinline__ f32x4 mfma16h(half8 a, half8 b, f32x4 c) {
    return __builtin_amdgcn_mfma_f32_16x16x32_f16(a, b, c, 0, 0, 0);
}
__device__ __forceinline__ f32x16 mfma32h(half8 a, half8 b, f32x16 c) {
    return __builtin_amdgcn_mfma_f32_32x32x16_f16(a, b, c, 0, 0, 0);
}

__device__ __forceinline__ unsigned pkh(float a, float b) {
    return __builtin_bit_cast(unsigned, __builtin_amdgcn_cvt_pkrtz(a, b));
}

#if __has_builtin(__builtin_amdgcn_exp2f)
__device__ __forceinline__ float fast_exp2(float x) { return __builtin_amdgcn_exp2f(x); }
#else
__device__ __forceinline__ float fast_exp2(float x) { return exp2f(x); }
#endif

// ---------------------------------------------------------------------------
// Kernel 1 (prep): blocks [0,3072) QKV projection; [3072,5120) mask pack
// (TRANSPOSED: bits[(b*32 + word)][q], coalesced attn reads); [5120,5632)
// Wo fp32->f16.  (unchanged, PASSED R6/R7)
// ---------------------------------------------------------------------------
__global__ __launch_bounds__(256) void prep_kernel(
    const float* __restrict__ q_in, const float* __restrict__ k_in,
    const float* __restrict__ v_in,
    const float* __restrict__ Wq, const float* __restrict__ Wk,
    const float* __restrict__ Wv, const float* __restrict__ Wo,
    const int* __restrict__ mask,
    short* __restrict__ Qb, short* __restrict__ Kb, short* __restrict__ Vt,
    short* __restrict__ Woh, unsigned long long* __restrict__ bits) {
    __shared__ short Al[64 * 72];
    __shared__ short Wl[64 * 72];
    __shared__ short Ol[64 * 72];
    int bx = blockIdx.x;
    int t = threadIdx.x;

    if (bx >= 3072) {
        if (bx < 5120) {
            int gw = (bx - 3072) * 4 + (t >> 6);
            int lane = t & 63;
            const int* src = mask + (size_t)gw * 1024 + lane;
            int row = gw >> 1;
            int bb = row >> 11, qq = row & 2047;
            int wbase = (gw & 1) * 16;
#pragma unroll
            for (int r = 0; r < 16; r++) {
                unsigned long long w = __ballot(src[r * 64] != 0);
                if (lane == 0)
                    bits[((size_t)(bb * 32 + wbase + r) << 11) + qq] = w;
            }
        } else {
            int i = (bx - 5120) * 256 + t;
            f32x4 a = reinterpret_cast<const f32x4*>(Wo)[i * 2];
            f32x4 b = reinterpret_cast<const f32x4*>(Wo)[i * 2 + 1];
            uint4 u = { pkh(a.x, a.y), pkh(a.z, a.w), pkh(b.x, b.y), pkh(b.z, b.w) };
            reinterpret_cast<uint4*>(Woh)[i] = u;
        }
        return;
    }

    int rt = bx & 31;
    int bh = (bx >> 5) & 31;
    int tz = bx >> 10;
    const float* src = (tz == 0 ? q_in : tz == 1 ? k_in : v_in)
                       + (size_t)bh * S_LEN * HD + (size_t)rt * 64 * HD;
    const float* W = (tz == 0 ? Wq : tz == 1 ? Wk : Wv);

#pragma unroll
    for (int r = 0; r < 4; r++) {
        int f4 = t + 256 * r;
        int row = f4 >> 4;
        int c4 = (f4 & 15) * 4;
        f32x4 a = reinterpret_cast<const f32x4*>(src)[f4];
        uint2 ua = { pkh(a.x, a.y), pkh(a.z, a.w) };
        *reinterpret_cast<uint2*>(&Al[row * 72 + c4]) = ua;
        f32x4 w = reinterpret_cast<const f32x4*>(W)[f4];
        uint2 uw = { pkh(w.x, w.y), pkh(w.z, w.w) };
        *reinterpret_cast<uint2*>(&Wl[row * 72 + c4]) = uw;
    }
    __syncthreads();

    int wave = t >> 6, lane = t & 63, quad = lane >> 4, col = lane & 15;
    half8 a0 = *reinterpret_cast<const half8*>(&Al[(wave * 16 + col) * 72 + quad * 8]);
    half8 a1 = *reinterpret_cast<const half8*>(&Al[(wave * 16 + col) * 72 + 32 + quad * 8]);

    const float C1 = 0.04508422002777448f;  // log2(e)/32
    float scl = (tz == 0) ? C1 : 1.0f;

    f32x4 acc[4];
#pragma unroll
    for (int jt = 0; jt < 4; jt++) {
        half8 b0 = *reinterpret_cast<const half8*>(&Wl[(jt * 16 + col) * 72 + quad * 8]);
        half8 b1 = *reinterpret_cast<const half8*>(&Wl[(jt * 16 + col) * 72 + 32 + quad * 8]);
        f32x4 c = {0.f, 0.f, 0.f, 0.f};
        c = mfma16h(a0, b0, c);
        c = mfma16h(a1, b1, c);
        acc[jt] = c;
    }
    __syncthreads();

    if (tz < 2) {
#pragma unroll
        for (int jt = 0; jt < 4; jt++)
#pragma unroll
            for (int i = 0; i < 4; i++)
                Ol[(wave * 16 + quad * 4 + i) * 72 + jt * 16 + col] =
                    __builtin_bit_cast(short, (_Float16)(acc[jt][i] * scl));
        __syncthreads();
        short* dst = (tz == 0 ? Qb : Kb) + (size_t)bh * S_LEN * HD + (size_t)rt * 64 * HD;
        int row = t >> 2, ck = (t & 3) * 16;
        short8 o0 = *reinterpret_cast<const short8*>(&Ol[row * 72 + ck]);
        short8 o1 = *reinterpret_cast<const short8*>(&Ol[row * 72 + ck + 8]);
        *reinterpret_cast<short8*>(&dst[row * 64 + ck]) = o0;
        *reinterpret_cast<short8*>(&dst[row * 64 + ck + 8]) = o1;
    } else {
#pragma unroll
        for (int jt = 0; jt < 4; jt++)
#pragma unroll
            for (int i = 0; i < 4; i++)
                Ol[(jt * 16 + col) * 72 + wave * 16 + quad * 4 + i] =
                    __builtin_bit_cast(short, (_Float16)acc[jt][i]);
        __syncthreads();
        short* dst = Vt + (size_t)bh * HD * S_LEN + rt * 64;
        int d = t >> 2, ck = (t & 3) * 16;
        short8 o0 = *reinterpret_cast<const short8*>(&Ol[d * 72 + ck]);
        short8 o1 = *reinterpret_cast<const short8*>(&Ol[d * 72 + ck + 8]);
        *reinterpret_cast<short8*>(&dst[(size_t)d * S_LEN + ck]) = o0;
        *reinterpret_cast<short8*>(&dst[(size_t)d * S_LEN + ck + 8]) = o1;
    }
}

// ---------------------------------------------------------------------------
// Kernel 2: flash attention, kv-PERMUTED K staging.
// 512 thr = 8 waves = 4 q-groups (32 q, BQ=128) x 2 kv-halves (additive).
// K rows staged at LDS row sigma^-1(kv) (within each 32-half) so the S^T
// C-layout regs hold kv = 16*l5 + r CONSECUTIVELY: packed P pairs ARE the
// PV B-frags (mfma#1 kv {0..7}u{16..23}, mfma#2 {8..15}u{24..31}); V-frag
// reads select col base h*32+16*l5+8*c.  No P LDS, no shuffles, no selects.
// Mask bit for reg r is simply bit (r + 16*l5) of the 32-bit half.
// ---------------------------------------------------------------------------
__global__ __launch_bounds__(512, 4) void attn_kernel(
    const short* __restrict__ Qb, const short* __restrict__ Kb,
    const short* __restrict__ Vt, const unsigned long long* __restrict__ mbits,
    short* __restrict__ Xb) {
    int qt = blockIdx.x;  // 0..15
    int bh = blockIdx.y;  // 0..31
    int b = bh >> 4;
    int t = threadIdx.x, wave = t >> 6, lane = t & 63;
    int g = wave & 3, h = wave >> 2;
    int l5 = lane >> 5, l31 = lane & 31;

    // LDS: [0,16384) shorts: K/V double buffer (buf i: K at i*8192, V at +4096)
    // [16384,16640): lbuf (128 floats). obuf (32KB fp32) overlays KV after loop.
    __shared__ short smem[16640];
    float* lbuf = (float*)(smem + 16384);

    const short* Qh = Qb + (size_t)bh * S_LEN * HD;
    const short* Kh = Kb + (size_t)bh * S_LEN * HD;
    const short* Vh = Vt + (size_t)bh * HD * S_LEN;
    int qbase = qt * 128 + g * 32;
    int q = qbase + l31;

    half8 qf[4];
#pragma unroll
    for (int kc = 0; kc < 4; kc++)
        qf[kc] = *reinterpret_cast<const half8*>(&Qh[(size_t)q * HD + kc * 16 + l5 * 8]);

    const unsigned long long* mcol = mbits + ((size_t)(b * 32) << 11);
    unsigned long long mwq = mcol[q];

    // ---- staging: 64 rows x 8 chunks each for K and V; 1 K + 1 V per thread
    int r0 = t >> 3, cc = t & 7;
    // K row permutation within each 32-half: sigma^-1(k)=(k&3)+((k&12)<<1)+((k&16)>>2)
    int kr = (r0 & 32) | ((r0 & 3) + ((r0 & 12) << 1) + ((r0 & 16) >> 2));
    int dstK = kr * 64 + ((cc ^ (kr & 7)) * 8);
    int dstV = r0 * 64 + ((cc ^ (r0 & 7)) * 8);
    const short* kg0 = Kh + r0 * HD + cc * 8;             // +4096 per tile
    const short* vg0 = Vh + (size_t)r0 * S_LEN + cc * 8;  // +64 per tile

    short8 pk = *reinterpret_cast<const short8*>(kg0);
    short8 pv = *reinterpret_cast<const short8*>(vg0);
    *reinterpret_cast<short8*>(&smem[dstK]) = pk;
    *reinterpret_cast<short8*>(&smem[4096 + dstV]) = pv;
    __syncthreads();

    f32x16 o0, o1;
#pragma unroll
    for (int r = 0; r < 16; r++) { o0[r] = 0.f; o1[r] = 0.f; }
    float l_acc = 0.f;
    int krow = h * 32 + l31;
    int mshift = h * 32 + 16 * l5;

    for (int kt = 0; kt < 32; kt++) {
        unsigned long long mwq_n;
        if (kt < 31) {
            pk = *reinterpret_cast<const short8*>(kg0 + (kt + 1) * 4096);
            pv = *reinterpret_cast<const short8*>(vg0 + (kt + 1) * 64);
            mwq_n = mcol[((size_t)(kt + 1) << 11) + q];
        }
        const short* Kbs = smem + (kt & 1) * 8192;
        const short* Vbs = Kbs + 4096;

        // ---- S^T = K·Q^T for this wave's kv-half (4 MFMAs) ----
        f32x16 s;
#pragma unroll
        for (int r = 0; r < 16; r++) s[r] = 0.f;
#pragma unroll
        for (int kc = 0; kc < 4; kc++) {
            half8 ka = *reinterpret_cast<const half8*>(
                &Kbs[krow * 64 + (((kc * 2 + l5) ^ (krow & 7)) * 8)]);
            s = mfma32h(ka, qf[kc], s);
        }
        // ---- lane-local softmax numerator; regs ARE kv-consecutive ----
        unsigned gs2 = (unsigned)(mwq >> mshift);
        unsigned uu[8];
#pragma unroll
        for (int i = 0; i < 8; i++) {
            float p0 = fast_exp2(((gs2 >> (2 * i)) & 1u) ? s[2 * i] : -200.0f);
            float p1 = fast_exp2(((gs2 >> (2 * i + 1)) & 1u) ? s[2 * i + 1] : -200.0f);
            l_acc += p0 + p1;
            uu[i] = pkh(p0, p1);
        }
        uint4 u0 = { uu[0], uu[1], uu[2], uu[3] };
        uint4 u1 = { uu[4], uu[5], uu[6], uu[7] };
        half8 pb0 = __builtin_bit_cast(half8, u0);  // kv {0..7}u{16..23} (+h*32)
        half8 pb1 = __builtin_bit_cast(half8, u1);  // kv {8..15}u{24..31}

        // ---- O^T += V^T·P^T (4 MFMAs; V col base h*32 + 16*l5 + 8*c) ----
#pragma unroll
        for (int c = 0; c < 2; c++) {
            half8 pb = c ? pb1 : pb0;
            {
                int ch = (h * 4 + l5 * 2 + c) ^ (l31 & 7);
                half8 va = *reinterpret_cast<const half8*>(&Vbs[l31 * 64 + ch * 8]);
                o0 = mfma32h(va, pb, o0);
            }
            {
                int vr = 32 + l31;
                int ch = (h * 4 + l5 * 2 + c) ^ (vr & 7);
                half8 va = *reinterpret_cast<const half8*>(&Vbs[vr * 64 + ch * 8]);
                o1 = mfma32h(va, pb, o1);
            }
        }
        // ---- stage next tile into other buffer, single barrier ----
        if (kt < 31) {
            short* nb = smem + ((kt + 1) & 1) * 8192;
            *reinterpret_cast<short8*>(&nb[dstK]) = pk;
            *reinterpret_cast<short8*>(&nb[4096 + dstV]) = pv;
            mwq = mwq_n;
        }
        __syncthreads();
    }

    // ---- combine kv-halves (additive split) ----
    l_acc += __shfl_xor(l_acc, 32);
    float* obuf = (float*)smem;  // 128 rows x 64 lanes fp32 = 32KB, overlays KV
    if (h == 1) {
#pragma unroll
        for (int r = 0; r < 16; r++) {
            obuf[(g * 32 + r) * 64 + lane] = o0[r];
            obuf[(g * 32 + 16 + r) * 64 + lane] = o1[r];
        }
        if (lane < 32) lbuf[g * 32 + lane] = l_acc;
    }
    __syncthreads();
    if (h == 0) {
        float inv = 1.0f / (l_acc + lbuf[g * 32 + l31]);
#pragma unroll
        for (int r = 0; r < 16; r++) {
            o0[r] = (o0[r] + obuf[(g * 32 + r) * 64 + lane]) * inv;
            o1[r] = (o1[r] + obuf[(g * 32 + 16 + r) * 64 + lane]) * inv;
        }
        short* Xrow = Xb + (size_t)bh * S_LEN * HD + (size_t)q * HD;
#pragma unroll
        for (int u = 0; u < 4; u++) {
            uint2 w0 = { pkh(o0[4 * u], o0[4 * u + 1]), pkh(o0[4 * u + 2], o0[4 * u + 3]) };
            *reinterpret_cast<uint2*>(&Xrow[4 * l5 + 8 * u]) = w0;
            uint2 w1 = { pkh(o1[4 * u], o1[4 * u + 1]), pkh(o1[4 * u + 2], o1[4 * u + 3]) };
            *reinterpret_cast<uint2*>(&Xrow[32 + 4 * l5 + 8 * u]) = w1;
        }
    }
}

// ---------------------------------------------------------------------------
// Kernel 3: out = X @ Wo^T + bo.  128m x 64n tile, 512 thr (8 waves x 16 m),
// BK=64, double-buffered staging, 1 barrier/step.  (unchanged, PASSED)
// ---------------------------------------------------------------------------
__global__ __launch_bounds__(512, 4) void final_kernel(
    const short* __restrict__ Xb, const short* __restrict__ Woh,
    const float* __restrict__ bo, float* __restrict__ out) {
    int nb = blockIdx.x;  // 0..15
    int mb = blockIdx.y;  // 0..31
    int t = threadIdx.x, wave = t >> 6, lane = t & 63, quad = lane >> 4, col = lane & 15;
    __shared__ short smem[24576];

    int m0 = mb * 128, n0 = nb * 64;
    int r0 = t >> 3, r1 = r0 + 64, cc = t & 7;
    int dx0 = r0 * 64 + ((cc ^ (r0 & 7)) * 8);
    int dx1 = r1 * 64 + ((cc ^ (r1 & 7)) * 8);
    const short* xg0 = Xb + (size_t)(m0 + r0) * EMB + cc * 8;   // +64 per step
    const short* xg1 = Xb + (size_t)(m0 + r1) * EMB + cc * 8;
    const short* wg0 = Woh + (size_t)(n0 + r0) * EMB + cc * 8;

    short8 px0 = *reinterpret_cast<const short8*>(xg0);
    short8 px1 = *reinterpret_cast<const short8*>(xg1);
    short8 pw0 = *reinterpret_cast<const short8*>(wg0);
    *reinterpret_cast<short8*>(&smem[dx0]) = px0;
    *reinterpret_cast<short8*>(&smem[dx1]) = px1;
    *reinterpret_cast<short8*>(&smem[16384 + dx0]) = pw0;
    __syncthreads();

    f32x4 acc[4];
#pragma unroll
    for (int nf = 0; nf < 4; nf++) acc[nf] = (f32x4){0.f, 0.f, 0.f, 0.f};
    int arow = wave * 16 + col;

    for (int s = 0; s < 16; s++) {
        if (s < 15) {
            px0 = *reinterpret_cast<const short8*>(xg0 + (s + 1) * 64);
            px1 = *reinterpret_cast<const short8*>(xg1 + (s + 1) * 64);
            pw0 = *reinterpret_cast<const short8*>(wg0 + (s + 1) * 64);
        }
        const short* Xs = smem + (s & 1) * 8192;
        const short* Ws = smem + 16384 + (s & 1) * 4096;
#pragma unroll
        for (int k2 = 0; k2 < 2; k2++) {
            half8 a = *reinterpret_cast<const half8*>(
                &Xs[arow * 64 + (((k2 * 4 + quad) ^ (arow & 7)) * 8)]);
#pragma unroll
            for (int nf = 0; nf < 4; nf++) {
                int brow = nf * 16 + col;
                half8 bf = *reinterpret_cast<const half8*>(
                    &Ws[brow * 64 + (((k2 * 4 + quad) ^ (brow & 7)) * 8)]);
                acc[nf] = mfma16h(a, bf, acc[nf]);
            }
        }
        if (s < 15) {
            short* Xn = smem + ((s + 1) & 1) * 8192;
            short* Wn = smem + 16384 + ((s + 1) & 1) * 4096;
            *reinterpret_cast<short8*>(&Xn[dx0]) = px0;
            *reinterpret_cast<short8*>(&Xn[dx1]) = px1;
            *reinterpret_cast<short8*>(&Wn[dx0]) = pw0;
        }
        __syncthreads();
    }

#pragma unroll
    for (int nf = 0; nf < 4; nf++) {
        int n = n0 + nf * 16 + col;
        float bb = bo[n];
        int rowb = m0 + wave * 16 + quad * 4;
#pragma unroll
        for (int i = 0; i < 4; i++)
            out[(size_t)(rowb + i) * EMB + n] = acc[nf][i] + bb;
    }
}

// ---------------------------------------------------------------------------
extern "C" void kernel_launch(void* const* d_in, const int* in_sizes, int n_in,
                              void* d_out, int out_size, void* d_ws, size_t ws_size,
                              hipStream_t stream) {
    const float* value = (const float*)d_in[0];
    const float* key_  = (const float*)d_in[1];
    const float* query = (const float*)d_in[2];
    const int*   mask  = (const int*)d_in[3];
    const float* Wq = (const float*)d_in[4];
    const float* Wk = (const float*)d_in[5];
    const float* Wv = (const float*)d_in[6];
    const float* Wo = (const float*)d_in[7];
    const float* bo = (const float*)d_in[8];
    float* out = (float*)d_out;

    char* ws = (char*)d_ws;
    short* Qb  = (short*)(ws);
    short* Kb  = (short*)(ws + (size_t)8  * 1048576);
    short* Vt  = (short*)(ws + (size_t)16 * 1048576);
    short* Xb  = (short*)(ws + (size_t)24 * 1048576);
    short* Woh = (short*)(ws + (size_t)32 * 1048576);
    unsigned long long* mbits =
        (unsigned long long*)(ws + (size_t)34 * 1048576);

    prep_kernel<<<dim3(3072 + 2048 + 512), dim3(256), 0, stream>>>(
        query, key_, value, Wq, Wk, Wv, Wo, mask, Qb, Kb, Vt, Woh, mbits);
    attn_kernel<<<dim3(S_LEN / 128, N_BH), dim3(512), 0, stream>>>(Qb, Kb, Vt, mbits, Xb);
    final_kernel<<<dim3(EMB / 64, (N_BATCH * S_LEN) / 128), dim3(512), 0, stream>>>(
        Xb, Woh, bo, out);
}